// Round 2
// baseline (178.912 us; speedup 1.0000x reference)
//
#include <hip/hip_runtime.h>
#include <stdint.h>

#define NN 4096
#define MM 8192
#define DD 512
#define KT 8  // 512 / BK, BK = 64

typedef __bf16 bf16x8 __attribute__((ext_vector_type(8)));
typedef __bf16 bf16x4 __attribute__((ext_vector_type(4)));
typedef float f32x4 __attribute__((ext_vector_type(4)));
typedef float f32x16 __attribute__((ext_vector_type(16)));

__device__ __forceinline__ void load_lds16(const void* g, void* l) {
  // async global -> LDS, 16B/lane; LDS dest must be wave-uniform base + lane*16
  // (our chunk index = uniform + lane by construction).
  __builtin_amdgcn_global_load_lds(
      (const __attribute__((address_space(1))) unsigned int*)g,
      (__attribute__((address_space(3))) unsigned int*)l, 16, 0, 0);
}

// 4 rows per 256-thread block, one wave per row. Fully-coalesced f32x4 loads,
// bf16x4 stores, exact fp32 row-norm, and out[]=IC init folded in.
__global__ __launch_bounds__(256) void convert_norm_kernel(
    const float* __restrict__ X, const float* __restrict__ SV,
    __bf16* __restrict__ Xb, __bf16* __restrict__ SVb,
    float* __restrict__ x2, float* __restrict__ sv2,
    float* __restrict__ out, const float* __restrict__ IC) {
  int wid = blockIdx.x * 4 + (threadIdx.x >> 6);
  int lane = threadIdx.x & 63;
  const float* src;
  __bf16* dst;
  float* nrm;
  if (wid < NN) {
    src = X + (size_t)wid * DD;
    dst = Xb + (size_t)wid * DD;
    nrm = x2 + wid;
    if (lane == 0) out[wid] = IC[0];
  } else {
    int r = wid - NN;
    src = SV + (size_t)r * DD;
    dst = SVb + (size_t)r * DD;
    nrm = sv2 + r;
  }
  const f32x4* s = (const f32x4*)src;
  f32x4 a = s[lane];       // elements 4l..4l+3
  f32x4 b = s[lane + 64];  // elements 256+4l..
  float sum = a.x * a.x + a.y * a.y + a.z * a.z + a.w * a.w +
              b.x * b.x + b.y * b.y + b.z * b.z + b.w * b.w;
  bf16x4 ca = {(__bf16)a.x, (__bf16)a.y, (__bf16)a.z, (__bf16)a.w};
  bf16x4 cb = {(__bf16)b.x, (__bf16)b.y, (__bf16)b.z, (__bf16)b.w};
  *(bf16x4*)(dst + 4 * lane) = ca;
  *(bf16x4*)(dst + 256 + 4 * lane) = cb;
#pragma unroll
  for (int m = 32; m >= 1; m >>= 1) sum += __shfl_xor(sum, m, 64);
  if (lane == 0) *nrm = sum;
}

// Producer/consumer GEMM: 6 waves. Waves 0-3 compute a 128x128 tile (each wave
// 64x64 via 2x2 of mfma_f32_32x32x16_bf16). Wave 4 stages A, wave 5 stages B
// for iteration kt+1 into the alternate LDS buffer while consumers compute kt.
// The producers' vmcnt drain at __syncthreads overlaps consumer compute.
// LDS chunk layout: [kc (0..7)][row (0..127)] 16B chunks -> staging is
// lane-contiguous AND fragment ds_read_b128 is conflict-free.
__global__ __launch_bounds__(384, 3) void rbf_gemm_kernel(
    const bf16x8* __restrict__ Xb, const bf16x8* __restrict__ SVb,
    const float* __restrict__ x2, const float* __restrict__ sv2,
    const float* __restrict__ DC, const float* __restrict__ gamma_p,
    float* __restrict__ out) {
  __shared__ bf16x8 As[2][1024];  // 2 x 16 KB (128 rows x 8 k-chunks)
  __shared__ bf16x8 Bs[2][1024];  // 2 x 16 KB

  const int t = threadIdx.x;
  const int lane = t & 63;
  const int wave = t >> 6;
  const int n0 = blockIdx.x * 128;
  const int m0 = blockIdx.y * 128;

  const int wave_m = wave & 1;   // consumer: m-dir
  const int wave_n = wave >> 1;  // consumer: n-dir
  const int l31 = lane & 31;
  const int lhi = lane >> 5;

  f32x16 acc[2][2];
#pragma unroll
  for (int i = 0; i < 2; ++i)
#pragma unroll
    for (int j = 0; j < 2; ++j)
#pragma unroll
      for (int r = 0; r < 16; ++r) acc[i][j][r] = 0.0f;

  // ---- prologue: fill buffer 0 with kt=0 ----
  if (wave == 4) {
#pragma unroll
    for (int it = 0; it < 16; ++it) {
      int c = it * 64 + lane;
      load_lds16(Xb + (size_t)(n0 + (c & 127)) * 64 + (c >> 7), &As[0][c]);
    }
  } else if (wave == 5) {
#pragma unroll
    for (int it = 0; it < 16; ++it) {
      int c = it * 64 + lane;
      load_lds16(SVb + (size_t)(m0 + (c & 127)) * 64 + (c >> 7), &Bs[0][c]);
    }
  }
  __syncthreads();

#pragma unroll
  for (int kt = 0; kt < KT; ++kt) {
    const int cur = kt & 1;
    const int nxt = cur ^ 1;
    if (wave == 4) {
      if (kt + 1 < KT) {
#pragma unroll
        for (int it = 0; it < 16; ++it) {
          int c = it * 64 + lane;
          load_lds16(Xb + (size_t)(n0 + (c & 127)) * 64 + (kt + 1) * 8 + (c >> 7),
                     &As[nxt][c]);
        }
      }
    } else if (wave == 5) {
      if (kt + 1 < KT) {
#pragma unroll
        for (int it = 0; it < 16; ++it) {
          int c = it * 64 + lane;
          load_lds16(SVb + (size_t)(m0 + (c & 127)) * 64 + (kt + 1) * 8 + (c >> 7),
                     &Bs[nxt][c]);
        }
      }
    } else {
#pragma unroll
      for (int ks = 0; ks < 4; ++ks) {
        const int kb = (ks * 2 + lhi) * 128 + l31;
        bf16x8 af0 = As[cur][kb + wave_n * 64];
        bf16x8 af1 = As[cur][kb + wave_n * 64 + 32];
        bf16x8 bf0 = Bs[cur][kb + wave_m * 64];
        bf16x8 bf1 = Bs[cur][kb + wave_m * 64 + 32];
        acc[0][0] = __builtin_amdgcn_mfma_f32_32x32x16_bf16(af0, bf0, acc[0][0], 0, 0, 0);
        acc[0][1] = __builtin_amdgcn_mfma_f32_32x32x16_bf16(af0, bf1, acc[0][1], 0, 0, 0);
        acc[1][0] = __builtin_amdgcn_mfma_f32_32x32x16_bf16(af1, bf0, acc[1][0], 0, 0, 0);
        acc[1][1] = __builtin_amdgcn_mfma_f32_32x32x16_bf16(af1, bf1, acc[1][1], 0, 0, 0);
      }
    }
    __syncthreads();
  }

  // ---- epilogue (compute waves only; no barriers past here) ----
  if (wave < 4) {
    const float g = gamma_p[0];
    const float c2 = g * 1.4426950408889634f;  // gamma * log2(e)

    float sv2v[2], dcv[2];
    const int colb = m0 + wave_m * 64 + l31;
    sv2v[0] = sv2[colb];
    dcv[0] = DC[colb];
    sv2v[1] = sv2[colb + 32];
    dcv[1] = DC[colb + 32];

#pragma unroll
    for (int i = 0; i < 2; ++i) {
      // C row = rowb + 8*g4 + r2, where reg = g4*4 + r2
      const int rowb = n0 + wave_n * 64 + i * 32 + 4 * lhi;
      float val[16];
#pragma unroll
      for (int g4 = 0; g4 < 4; ++g4) {
        f32x4 xv = *(const f32x4*)(x2 + rowb + 8 * g4);
#pragma unroll
        for (int r2 = 0; r2 < 4; ++r2) {
          const int reg = g4 * 4 + r2;
          float v = 0.0f;
#pragma unroll
          for (int j = 0; j < 2; ++j) {
            float d2 = xv[r2] + sv2v[j] - 2.0f * acc[i][j][reg];
            d2 = fmaxf(d2, 0.0f);
            v += exp2f(-c2 * d2) * dcv[j];
          }
          val[reg] = v;
        }
      }
      // reduce over the 32 column-lanes (lane bits 0..4)
#pragma unroll
      for (int m = 1; m < 32; m <<= 1)
#pragma unroll
        for (int reg = 0; reg < 16; ++reg)
          val[reg] += __shfl_xor(val[reg], m, 64);
      if (l31 == 0) {
#pragma unroll
        for (int g4 = 0; g4 < 4; ++g4)
#pragma unroll
          for (int r2 = 0; r2 < 4; ++r2)
            atomicAdd(&out[rowb + 8 * g4 + r2], val[g4 * 4 + r2]);
      }
    }
  }
}

extern "C" void kernel_launch(void* const* d_in, const int* in_sizes, int n_in,
                              void* d_out, int out_size, void* d_ws, size_t ws_size,
                              hipStream_t stream) {
  const float* X = (const float*)d_in[0];
  const float* SV = (const float*)d_in[1];
  const float* DC = (const float*)d_in[2];
  const float* IC = (const float*)d_in[3];
  const float* gamma = (const float*)d_in[4];
  float* out = (float*)d_out;

  char* ws = (char*)d_ws;
  __bf16* Xb = (__bf16*)ws;                                   // 4 MB
  __bf16* SVb = (__bf16*)(ws + (size_t)NN * DD * 2);          // 8 MB
  float* x2 = (float*)(ws + (size_t)(NN + MM) * DD * 2);      // 16 KB
  float* sv2 = x2 + NN;                                       // 32 KB

  convert_norm_kernel<<<(NN + MM) / 4, 256, 0, stream>>>(X, SV, Xb, SVb, x2, sv2, out, IC);
  dim3 grid(NN / 128, MM / 128);
  rbf_gemm_kernel<<<grid, 384, 0, stream>>>((const bf16x8*)Xb, (const bf16x8*)SVb,
                                            x2, sv2, DC, gamma, out);
}

// Round 3
// 151.226 us; speedup vs baseline: 1.1831x; 1.1831x over previous
//
#include <hip/hip_runtime.h>
#include <stdint.h>

#define NN 4096
#define MM 8192
#define DD 512
#define KT 8  // 512 / BK, BK = 64

typedef __bf16 bf16x8 __attribute__((ext_vector_type(8)));
typedef __bf16 bf16x4 __attribute__((ext_vector_type(4)));
typedef float f32x4 __attribute__((ext_vector_type(4)));
typedef float f32x16 __attribute__((ext_vector_type(16)));

__device__ __forceinline__ void load_lds16(const void* g, void* l) {
  // async global -> LDS, 16B/lane; LDS dest must be wave-uniform base + lane*16
  // (our chunk index = uniform + lane by construction).
  __builtin_amdgcn_global_load_lds(
      (const __attribute__((address_space(1))) unsigned int*)g,
      (__attribute__((address_space(3))) unsigned int*)l, 16, 0, 0);
}

// 4 rows per 256-thread block, one wave per row. Fully-coalesced f32x4 loads,
// bf16x4 stores, exact fp32 row-norm, and out[]=IC init folded in.
__global__ __launch_bounds__(256) void convert_norm_kernel(
    const float* __restrict__ X, const float* __restrict__ SV,
    __bf16* __restrict__ Xb, __bf16* __restrict__ SVb,
    float* __restrict__ x2, float* __restrict__ sv2,
    float* __restrict__ out, const float* __restrict__ IC) {
  int wid = blockIdx.x * 4 + (threadIdx.x >> 6);
  int lane = threadIdx.x & 63;
  const float* src;
  __bf16* dst;
  float* nrm;
  if (wid < NN) {
    src = X + (size_t)wid * DD;
    dst = Xb + (size_t)wid * DD;
    nrm = x2 + wid;
    if (lane == 0) out[wid] = IC[0];
  } else {
    int r = wid - NN;
    src = SV + (size_t)r * DD;
    dst = SVb + (size_t)r * DD;
    nrm = sv2 + r;
  }
  const f32x4* s = (const f32x4*)src;
  f32x4 a = s[lane];       // elements 4l..4l+3
  f32x4 b = s[lane + 64];  // elements 256+4l..
  float sum = a.x * a.x + a.y * a.y + a.z * a.z + a.w * a.w +
              b.x * b.x + b.y * b.y + b.z * b.z + b.w * b.w;
  bf16x4 ca = {(__bf16)a.x, (__bf16)a.y, (__bf16)a.z, (__bf16)a.w};
  bf16x4 cb = {(__bf16)b.x, (__bf16)b.y, (__bf16)b.z, (__bf16)b.w};
  *(bf16x4*)(dst + 4 * lane) = ca;
  *(bf16x4*)(dst + 256 + 4 * lane) = cb;
#pragma unroll
  for (int m = 32; m >= 1; m >>= 1) sum += __shfl_xor(sum, m, 64);
  if (lane == 0) *nrm = sum;
}

// Producer/consumer GEMM: 6 waves. Waves 0-3 compute a 128x128 tile (each wave
// 64x64 via 2x2 of mfma_f32_32x32x16_bf16). Wave 4 stages A, wave 5 stages B
// for kt+1 into the alternate LDS buffer while consumers compute kt.
//
// LDS layout (per matrix/buffer): 128 rows x 8 chunks of 16 B, XOR-swizzled:
//   phys(row, kg) = row*8 + (kg ^ (row & 7))
// Staging instruction `it` covers rows 8*it..8*it+7: lane l -> row 8*it+(l>>3),
// global chunk kg = (l&7) ^ ((l>>3)&7), LDS index it*64+l. Per 8-lane group the
// global addresses permute one contiguous 128 B span -> fully coalesced
// (8 cache lines/instr, was 64). Fragment ds_read_b128 hits each bank exactly
// 4x per 32-lane half (the b128 minimum) -> no serialization beyond minimum.
__global__ __launch_bounds__(384, 3) void rbf_gemm_kernel(
    const bf16x8* __restrict__ Xb, const bf16x8* __restrict__ SVb,
    const float* __restrict__ x2, const float* __restrict__ sv2,
    const float* __restrict__ DC, const float* __restrict__ gamma_p,
    float* __restrict__ out) {
  __shared__ bf16x8 As[2][1024];  // 2 x 16 KB
  __shared__ bf16x8 Bs[2][1024];  // 2 x 16 KB

  const int t = threadIdx.x;
  const int lane = t & 63;
  const int wave = t >> 6;
  const int n0 = blockIdx.x * 128;
  const int m0 = blockIdx.y * 128;

  const int wave_m = wave & 1;   // consumer: m-dir
  const int wave_n = wave >> 1;  // consumer: n-dir
  const int l31 = lane & 31;
  const int lhi = lane >> 5;

  // staging decomposition (producers)
  const int rg = lane >> 3;              // row within 8-row group
  const int perm = (lane & 7) ^ rg;      // permuted k-slot (XOR swizzle)

  f32x16 acc[2][2];
#pragma unroll
  for (int i = 0; i < 2; ++i)
#pragma unroll
    for (int j = 0; j < 2; ++j)
#pragma unroll
      for (int r = 0; r < 16; ++r) acc[i][j][r] = 0.0f;

  // ---- prologue: fill buffer 0 with kt=0 ----
  if (wave == 4) {
#pragma unroll
    for (int it = 0; it < 16; ++it)
      load_lds16(Xb + (size_t)(n0 + it * 8 + rg) * 64 + perm, &As[0][it * 64 + lane]);
  } else if (wave == 5) {
#pragma unroll
    for (int it = 0; it < 16; ++it)
      load_lds16(SVb + (size_t)(m0 + it * 8 + rg) * 64 + perm, &Bs[0][it * 64 + lane]);
  }
  __syncthreads();

#pragma unroll
  for (int kt = 0; kt < KT; ++kt) {
    const int cur = kt & 1;
    const int nxt = cur ^ 1;
    if (wave == 4) {
      if (kt + 1 < KT) {
#pragma unroll
        for (int it = 0; it < 16; ++it)
          load_lds16(Xb + (size_t)(n0 + it * 8 + rg) * 64 + (kt + 1) * 8 + perm,
                     &As[nxt][it * 64 + lane]);
      }
    } else if (wave == 5) {
      if (kt + 1 < KT) {
#pragma unroll
        for (int it = 0; it < 16; ++it)
          load_lds16(SVb + (size_t)(m0 + it * 8 + rg) * 64 + (kt + 1) * 8 + perm,
                     &Bs[nxt][it * 64 + lane]);
      }
    } else {
#pragma unroll
      for (int ks = 0; ks < 4; ++ks) {
        const int kc = ks * 2 + lhi;  // k-chunk 0..7
        const int sw = kc ^ (l31 & 7);
        const int ra = (wave_n * 64 + l31) * 8;
        const int rb = (wave_m * 64 + l31) * 8;
        bf16x8 af0 = As[cur][ra + sw];
        bf16x8 af1 = As[cur][ra + 256 + sw];  // +32 rows
        bf16x8 bf0 = Bs[cur][rb + sw];
        bf16x8 bf1 = Bs[cur][rb + 256 + sw];
        acc[0][0] = __builtin_amdgcn_mfma_f32_32x32x16_bf16(af0, bf0, acc[0][0], 0, 0, 0);
        acc[0][1] = __builtin_amdgcn_mfma_f32_32x32x16_bf16(af0, bf1, acc[0][1], 0, 0, 0);
        acc[1][0] = __builtin_amdgcn_mfma_f32_32x32x16_bf16(af1, bf0, acc[1][0], 0, 0, 0);
        acc[1][1] = __builtin_amdgcn_mfma_f32_32x32x16_bf16(af1, bf1, acc[1][1], 0, 0, 0);
      }
    }
    __syncthreads();
  }

  // ---- epilogue (compute waves only; no barriers past here) ----
  if (wave < 4) {
    const float g = gamma_p[0];
    const float c2 = g * 1.4426950408889634f;  // gamma * log2(e)

    float sv2v[2], dcv[2];
    const int colb = m0 + wave_m * 64 + l31;
    sv2v[0] = sv2[colb];
    dcv[0] = DC[colb];
    sv2v[1] = sv2[colb + 32];
    dcv[1] = DC[colb + 32];

#pragma unroll
    for (int i = 0; i < 2; ++i) {
      // C row = rowb + 8*g4 + r2, where reg = g4*4 + r2
      const int rowb = n0 + wave_n * 64 + i * 32 + 4 * lhi;
      float val[16];
#pragma unroll
      for (int g4 = 0; g4 < 4; ++g4) {
        f32x4 xv = *(const f32x4*)(x2 + rowb + 8 * g4);
#pragma unroll
        for (int r2 = 0; r2 < 4; ++r2) {
          const int reg = g4 * 4 + r2;
          float v = 0.0f;
#pragma unroll
          for (int j = 0; j < 2; ++j) {
            float d2 = xv[r2] + sv2v[j] - 2.0f * acc[i][j][reg];
            d2 = fmaxf(d2, 0.0f);
            v += exp2f(-c2 * d2) * dcv[j];
          }
          val[reg] = v;
        }
      }
      // reduce over the 32 column-lanes (lane bits 0..4)
#pragma unroll
      for (int m = 1; m < 32; m <<= 1)
#pragma unroll
        for (int reg = 0; reg < 16; ++reg)
          val[reg] += __shfl_xor(val[reg], m, 64);
      if (l31 == 0) {
#pragma unroll
        for (int g4 = 0; g4 < 4; ++g4)
#pragma unroll
          for (int r2 = 0; r2 < 4; ++r2)
            atomicAdd(&out[rowb + 8 * g4 + r2], val[g4 * 4 + r2]);
      }
    }
  }
}

extern "C" void kernel_launch(void* const* d_in, const int* in_sizes, int n_in,
                              void* d_out, int out_size, void* d_ws, size_t ws_size,
                              hipStream_t stream) {
  const float* X = (const float*)d_in[0];
  const float* SV = (const float*)d_in[1];
  const float* DC = (const float*)d_in[2];
  const float* IC = (const float*)d_in[3];
  const float* gamma = (const float*)d_in[4];
  float* out = (float*)d_out;

  char* ws = (char*)d_ws;
  __bf16* Xb = (__bf16*)ws;                                   // 4 MB
  __bf16* SVb = (__bf16*)(ws + (size_t)NN * DD * 2);          // 8 MB
  float* x2 = (float*)(ws + (size_t)(NN + MM) * DD * 2);      // 16 KB
  float* sv2 = x2 + NN;                                       // 32 KB

  convert_norm_kernel<<<(NN + MM) / 4, 256, 0, stream>>>(X, SV, Xb, SVb, x2, sv2, out, IC);
  dim3 grid(NN / 128, MM / 128);
  rbf_gemm_kernel<<<grid, 384, 0, stream>>>((const bf16x8*)Xb, (const bf16x8*)SVb,
                                            x2, sv2, DC, gamma, out);
}

// Round 4
// 136.670 us; speedup vs baseline: 1.3091x; 1.1065x over previous
//
#include <hip/hip_runtime.h>
#include <stdint.h>

#define NN 4096
#define MM 8192
#define DD 512
#define KT 8  // 512 / BK, BK = 64

typedef __bf16 bf16x8 __attribute__((ext_vector_type(8)));
typedef __bf16 bf16x4 __attribute__((ext_vector_type(4)));
typedef float f32x4 __attribute__((ext_vector_type(4)));
typedef float f32x16 __attribute__((ext_vector_type(16)));

__device__ __forceinline__ void load_lds16(const void* g, void* l) {
  // async global -> LDS, 16B/lane; LDS dest must be wave-uniform base + lane*16
  // (our chunk index = uniform + lane by construction).
  __builtin_amdgcn_global_load_lds(
      (const __attribute__((address_space(1))) unsigned int*)g,
      (__attribute__((address_space(3))) unsigned int*)l, 16, 0, 0);
}

// 4 rows per 256-thread block, one wave per row. Fully-coalesced f32x4 loads,
// bf16x4 stores, exact fp32 row-norm, and out[]=IC init folded in.
__global__ __launch_bounds__(256) void convert_norm_kernel(
    const float* __restrict__ X, const float* __restrict__ SV,
    __bf16* __restrict__ Xb, __bf16* __restrict__ SVb,
    float* __restrict__ x2, float* __restrict__ sv2,
    float* __restrict__ out, const float* __restrict__ IC) {
  int wid = blockIdx.x * 4 + (threadIdx.x >> 6);
  int lane = threadIdx.x & 63;
  const float* src;
  __bf16* dst;
  float* nrm;
  if (wid < NN) {
    src = X + (size_t)wid * DD;
    dst = Xb + (size_t)wid * DD;
    nrm = x2 + wid;
    if (lane == 0) out[wid] = IC[0];
  } else {
    int r = wid - NN;
    src = SV + (size_t)r * DD;
    dst = SVb + (size_t)r * DD;
    nrm = sv2 + r;
  }
  const f32x4* s = (const f32x4*)src;
  f32x4 a = s[lane];       // elements 4l..4l+3
  f32x4 b = s[lane + 64];  // elements 256+4l..
  float sum = a.x * a.x + a.y * a.y + a.z * a.z + a.w * a.w +
              b.x * b.x + b.y * b.y + b.z * b.z + b.w * b.w;
  bf16x4 ca = {(__bf16)a.x, (__bf16)a.y, (__bf16)a.z, (__bf16)a.w};
  bf16x4 cb = {(__bf16)b.x, (__bf16)b.y, (__bf16)b.z, (__bf16)b.w};
  *(bf16x4*)(dst + 4 * lane) = ca;
  *(bf16x4*)(dst + 256 + 4 * lane) = cb;
#pragma unroll
  for (int m = 32; m >= 1; m >>= 1) sum += __shfl_xor(sum, m, 64);
  if (lane == 0) *nrm = sum;
}

// All-compute GEMM: 4 waves (2x2), each wave a 64x64 sub-tile via 2x2 of
// mfma_f32_32x32x16_bf16. Single 32 KB LDS buffer -> 4 blocks/CU resident;
// cross-block wave overlap hides staging latency and barrier drains.
//
// LDS layout (per matrix): 128 rows x 8 chunks of 16 B, XOR-swizzled:
//   phys(row, kg) = row*8 + (kg ^ (row & 7))
// Cooperative staging: chunk c = it*256 + t; row = c>>3, kg = (c&7)^(row&7).
// Per 8-lane group the global addresses permute one contiguous 128 B span ->
// fully coalesced; LDS dest index == uniform + lane (global_load_lds constraint).
// Fragment ds_read_b128: bank = f(kc ^ (l31&7)) -> each 8-lane group covers
// all 32 banks once -> balanced.
__global__ __launch_bounds__(256, 4) void rbf_gemm_kernel(
    const bf16x8* __restrict__ Xb, const bf16x8* __restrict__ SVb,
    const float* __restrict__ x2, const float* __restrict__ sv2,
    const float* __restrict__ DC, const float* __restrict__ gamma_p,
    float* __restrict__ out) {
  __shared__ bf16x8 As[1024];  // 16 KB
  __shared__ bf16x8 Bs[1024];  // 16 KB

  const int t = threadIdx.x;
  const int lane = t & 63;
  const int wave = t >> 6;
  const int n0 = blockIdx.x * 128;
  const int m0 = blockIdx.y * 128;

  const int wave_m = wave & 1;   // m-dir of C
  const int wave_n = wave >> 1;  // n-dir of C
  const int l31 = lane & 31;
  const int lhi = lane >> 5;

  // staging decomposition: chunk c_it = it*256 + t
  const int srow = t >> 3;            // row contribution for it=0 (rows 0..31)
  const int sslot = t & 7;

  f32x16 acc[2][2];
#pragma unroll
  for (int i = 0; i < 2; ++i)
#pragma unroll
    for (int j = 0; j < 2; ++j)
#pragma unroll
      for (int r = 0; r < 16; ++r) acc[i][j][r] = 0.0f;

  for (int kt = 0; kt < KT; ++kt) {
    // ---- cooperative staging: 4 instrs A + 4 instrs B per thread ----
#pragma unroll
    for (int it = 0; it < 4; ++it) {
      const int c = it * 256 + t;
      const int row = it * 32 + srow;
      const int kg = sslot ^ (row & 7);
      load_lds16(Xb + (size_t)(n0 + row) * 64 + kt * 8 + kg, &As[c]);
      load_lds16(SVb + (size_t)(m0 + row) * 64 + kt * 8 + kg, &Bs[c]);
    }
    __syncthreads();
    // ---- compute ----
#pragma unroll
    for (int ks = 0; ks < 4; ++ks) {
      const int kc = ks * 2 + lhi;        // k-chunk 0..7
      const int sw = kc ^ (l31 & 7);
      const int ra = (wave_n * 64 + l31) * 8;
      const int rb = (wave_m * 64 + l31) * 8;
      bf16x8 af0 = As[ra + sw];
      bf16x8 af1 = As[ra + 256 + sw];  // +32 rows
      bf16x8 bf0 = Bs[rb + sw];
      bf16x8 bf1 = Bs[rb + 256 + sw];
      acc[0][0] = __builtin_amdgcn_mfma_f32_32x32x16_bf16(af0, bf0, acc[0][0], 0, 0, 0);
      acc[0][1] = __builtin_amdgcn_mfma_f32_32x32x16_bf16(af0, bf1, acc[0][1], 0, 0, 0);
      acc[1][0] = __builtin_amdgcn_mfma_f32_32x32x16_bf16(af1, bf0, acc[1][0], 0, 0, 0);
      acc[1][1] = __builtin_amdgcn_mfma_f32_32x32x16_bf16(af1, bf1, acc[1][1], 0, 0, 0);
    }
    __syncthreads();
  }

  // ---- epilogue (no barriers) ----
  const float g = gamma_p[0];
  const float c2 = g * 1.4426950408889634f;  // gamma * log2(e)

  float sv2v[2], dcv[2];
  const int colb = m0 + wave_m * 64 + l31;
  sv2v[0] = sv2[colb];
  dcv[0] = DC[colb];
  sv2v[1] = sv2[colb + 32];
  dcv[1] = DC[colb + 32];

#pragma unroll
  for (int i = 0; i < 2; ++i) {
    // C row = rowb + 8*g4 + r2, where reg = g4*4 + r2
    const int rowb = n0 + wave_n * 64 + i * 32 + 4 * lhi;
    float val[16];
#pragma unroll
    for (int g4 = 0; g4 < 4; ++g4) {
      f32x4 xv = *(const f32x4*)(x2 + rowb + 8 * g4);
#pragma unroll
      for (int r2 = 0; r2 < 4; ++r2) {
        const int reg = g4 * 4 + r2;
        float v = 0.0f;
#pragma unroll
        for (int j = 0; j < 2; ++j) {
          float d2 = xv[r2] + sv2v[j] - 2.0f * acc[i][j][reg];
          d2 = fmaxf(d2, 0.0f);
          v += exp2f(-c2 * d2) * dcv[j];
        }
        val[reg] = v;
      }
    }
    // reduce over the 32 column-lanes (lane bits 0..4)
#pragma unroll
    for (int m = 1; m < 32; m <<= 1)
#pragma unroll
      for (int reg = 0; reg < 16; ++reg)
        val[reg] += __shfl_xor(val[reg], m, 64);
    if (l31 == 0) {
#pragma unroll
      for (int g4 = 0; g4 < 4; ++g4)
#pragma unroll
        for (int r2 = 0; r2 < 4; ++r2)
          atomicAdd(&out[rowb + 8 * g4 + r2], val[g4 * 4 + r2]);
    }
  }
}

extern "C" void kernel_launch(void* const* d_in, const int* in_sizes, int n_in,
                              void* d_out, int out_size, void* d_ws, size_t ws_size,
                              hipStream_t stream) {
  const float* X = (const float*)d_in[0];
  const float* SV = (const float*)d_in[1];
  const float* DC = (const float*)d_in[2];
  const float* IC = (const float*)d_in[3];
  const float* gamma = (const float*)d_in[4];
  float* out = (float*)d_out;

  char* ws = (char*)d_ws;
  __bf16* Xb = (__bf16*)ws;                                   // 4 MB
  __bf16* SVb = (__bf16*)(ws + (size_t)NN * DD * 2);          // 8 MB
  float* x2 = (float*)(ws + (size_t)(NN + MM) * DD * 2);      // 16 KB
  float* sv2 = x2 + NN;                                       // 32 KB

  convert_norm_kernel<<<(NN + MM) / 4, 256, 0, stream>>>(X, SV, Xb, SVb, x2, sv2, out, IC);
  dim3 grid(NN / 128, MM / 128);
  rbf_gemm_kernel<<<grid, 256, 0, stream>>>((const bf16x8*)Xb, (const bf16x8*)SVb,
                                            x2, sv2, DC, gamma, out);
}